// Round 1
// baseline (1469.910 us; speedup 1.0000x reference)
//
#include <hip/hip_runtime.h>
#include <math.h>

// Problem dims
#define BATCH 8
#define CH 6
#define HW 4096
#define FF 9216
#define RC 48            // BATCH*CH rows
#define LOG2E 1.44269504088896340736f
#define LN100 4.6051701859880913680f

// ---------------- prep: build featT[k][48] and xT[b][n][6] ----------------
__global__ __launch_bounds__(256) void prep_kernel(
    const float* __restrict__ x, const float* __restrict__ feature,
    float* __restrict__ featT, float* __restrict__ xT)
{
    int i = blockIdx.x * 256 + threadIdx.x;
    if (i < FF * RC) {
        int k = i / RC, r = i - k * RC;
        featT[i] = feature[(size_t)r * FF + k];
    } else {
        int t = i - FF * RC;
        if (t < BATCH * HW * CH) {
            int c = t % CH;
            int n = (t / CH) & (HW - 1);
            int b = t / (HW * CH);
            xT[t] = x[((size_t)(b * CH + c)) * HW + n];
        }
    }
}

// ---------------- skinny GEMM: out[j] += W[j,:] . AT[:,r] for r in 0..47 --
// W: [N][K] row-major. AT: [K][48]. part: [nchunks][N][48].
// block: 256 thr = 64 j-columns x 4 wave-k-segments. kchunk multiple of 128.
__global__ __launch_bounds__(256) void skinny48_gemm(
    const float* __restrict__ W, const float* __restrict__ AT,
    float* __restrict__ part, int K, int kchunk)
{
    __shared__ float lds[64 * 133];
    const int t = threadIdx.x;
    const int jl = t & 63;        // j within tile (compute)
    const int w  = t >> 6;        // wave id = k sub-segment
    const int j0 = blockIdx.x * 64;
    const int kbase = blockIdx.y * kchunk;
    const int ntiles = kchunk >> 7;   // tiles of 128 k

    float acc[RC];
#pragma unroll
    for (int r = 0; r < RC; ++r) acc[r] = 0.f;

    const int srow = t >> 2;          // staging row 0..63
    const int sseg = (t & 3) * 32;    // staging k-offset
    const float* __restrict__ wsrc = W + (size_t)(j0 + srow) * K + kbase + sseg;

    for (int tile = 0; tile < ntiles; ++tile) {
        // ---- stage [64 j][128 k] tile, coalesced ----
        const float4* s4 = (const float4*)(wsrc + (size_t)tile * 128);
        float* d = lds + srow * 133 + sseg;
#pragma unroll
        for (int q = 0; q < 8; ++q) {
            float4 v = s4[q];
            d[q * 4 + 0] = v.x; d[q * 4 + 1] = v.y;
            d[q * 4 + 2] = v.z; d[q * 4 + 3] = v.w;
        }
        __syncthreads();
        // ---- compute: wave w handles kk in [w*32, w*32+32) of this tile ----
        const float* __restrict__ arow = AT + (size_t)(kbase + tile * 128 + w * 32) * RC;
        const float* lrow = lds + jl * 133 + w * 32;
#pragma unroll 4
        for (int kk = 0; kk < 32; ++kk) {
            float wv = lrow[kk];
            const float* __restrict__ a = arow + kk * RC;  // wave-uniform -> s_load
#pragma unroll
            for (int r = 0; r < RC; ++r) acc[r] = fmaf(a[r], wv, acc[r]);
        }
        __syncthreads();
    }

    // ---- reduce the 4 wave partials through LDS ----
    float* scratch = lds;   // [64][49]
    for (int src = 1; src < 4; ++src) {
        if (w == src) {
#pragma unroll
            for (int r = 0; r < RC; ++r) scratch[jl * 49 + r] = acc[r];
        }
        __syncthreads();
        if (w == 0) {
#pragma unroll
            for (int r = 0; r < RC; ++r) acc[r] += scratch[jl * 49 + r];
        }
        __syncthreads();
    }
    if (w == 0) {
        float* dst = part + ((size_t)blockIdx.y * (gridDim.x * 64) + j0 + jl) * RC;
#pragma unroll
        for (int r = 0; r < RC; r += 4)
            *(float4*)(dst + r) = make_float4(acc[r], acc[r + 1], acc[r + 2], acc[r + 3]);
    }
}

// ---------------- reduce1: hT[j][r] = relu(sum_c p1 + b1[j]) ----------------
__global__ __launch_bounds__(256) void reduce_relu(
    const float* __restrict__ part, const float* __restrict__ bias,
    float* __restrict__ hT, int nchunks)
{
    int i = blockIdx.x * 256 + threadIdx.x;
    const int total = FF * RC;
    if (i >= total) return;
    float s = 0.f;
    for (int c = 0; c < nchunks; ++c) s += part[(size_t)c * total + i];
    int j = i / RC;
    s += bias[j];
    hT[i] = fmaxf(s, 0.f);
}

// ---- reduce2: fTs[b][m][c] = (sum_c p2 + b2[m]) * ls[m] * LOG2E -----------
__global__ __launch_bounds__(256) void reduce_scale(
    const float* __restrict__ part, const float* __restrict__ bias,
    const float* __restrict__ logit_scale, float* __restrict__ fTs, int nchunks)
{
    int i = blockIdx.x * 256 + threadIdx.x;
    const int total = HW * RC;
    if (i >= total) return;
    float s = 0.f;
    for (int c = 0; c < nchunks; ++c) s += part[(size_t)c * total + i];
    int m = i / RC, rc = i - m * RC;
    int b = rc / CH, cc = rc - b * CH;
    float lv = fminf(logit_scale[m], LN100);
    float ls = __builtin_amdgcn_exp2f(lv * LOG2E);
    s = (s + bias[m]) * ls * LOG2E;
    fTs[((size_t)b * HW + m) * CH + cc] = s;
}

// ---------------- pass A: column sums D over an n-chunk --------------------
__global__ __launch_bounds__(256) void colsum_kernel(
    const float* __restrict__ fTs, const float* __restrict__ xT,
    float* __restrict__ Dpart)
{
    int m = blockIdx.x * 256 + threadIdx.x;
    int b = blockIdx.y;
    int ns = blockIdx.z;
    const float* f = fTs + ((size_t)b * HW + m) * CH;
    float s0 = f[0], s1 = f[1], s2 = f[2], s3 = f[3], s4 = f[4], s5 = f[5];
    const float* __restrict__ xb = xT + (size_t)b * HW * CH + (size_t)ns * 512 * CH;
    float D = 0.f;
#pragma unroll 4
    for (int n = 0; n < 512; ++n) {
        const float* __restrict__ xn = xb + n * CH;   // wave-uniform -> s_load
        float a = fmaf(s0, xn[0], fmaf(s1, xn[1], fmaf(s2, xn[2],
                  fmaf(s3, xn[3], fmaf(s4, xn[4], s5 * xn[5])))));
        D += __builtin_amdgcn_exp2f(a);
    }
    Dpart[((size_t)b * 8 + ns) * HW + m] = D;
}

__global__ __launch_bounds__(256) void combineD_kernel(
    const float* __restrict__ Dpart, float* __restrict__ R)
{
    int i = blockIdx.x * 256 + threadIdx.x;
    if (i >= BATCH * HW) return;
    int b = i >> 12, m = i & (HW - 1);
    float s = 0.f;
    for (int ns = 0; ns < 8; ++ns) s += Dpart[((size_t)b * 8 + ns) * HW + m];
    R[i] = 1.0f / s;
}

// -------- pass B: out[b,n,c] = LN( sum_m exp(t) * R_m * x[c,m] ) ----------
__global__ __launch_bounds__(256) void attn_out_kernel(
    const float* __restrict__ fTs, const float* __restrict__ xT,
    const float* __restrict__ R, const float* __restrict__ nw,
    const float* __restrict__ nb, float* __restrict__ out)
{
    int b = blockIdx.y;
    int wv = threadIdx.x >> 6;
    int lane = threadIdx.x & 63;
    int n0 = (blockIdx.x * 4 + wv) * 8;

    const float* __restrict__ xb = xT + (size_t)b * HW * CH;
    // hoist the 8 wave-uniform xn rows
    float xn[8][6];
#pragma unroll
    for (int n = 0; n < 8; ++n)
#pragma unroll
        for (int c = 0; c < 6; ++c) xn[n][c] = xb[(size_t)(n0 + n) * CH + c];

    const float* __restrict__ frb = fTs + (size_t)b * HW * CH;
    const float* __restrict__ Rb = R + b * HW;

    float acc[8][6];
#pragma unroll
    for (int n = 0; n < 8; ++n)
#pragma unroll
        for (int c = 0; c < 6; ++c) acc[n][c] = 0.f;

    for (int i = 0; i < 64; ++i) {
        int m = i * 64 + lane;
        const float* f = frb + (size_t)m * CH;
        float f0 = f[0], f1 = f[1], f2 = f[2], f3 = f[3], f4 = f[4], f5 = f[5];
        const float* xm = xb + (size_t)m * CH;
        float r = Rb[m];
        float x0 = xm[0] * r, x1 = xm[1] * r, x2 = xm[2] * r;
        float x3 = xm[3] * r, x4 = xm[4] * r, x5 = xm[5] * r;
#pragma unroll
        for (int n = 0; n < 8; ++n) {
            float a = fmaf(f0, xn[n][0], fmaf(f1, xn[n][1], fmaf(f2, xn[n][2],
                      fmaf(f3, xn[n][3], fmaf(f4, xn[n][4], f5 * xn[n][5])))));
            float p = __builtin_amdgcn_exp2f(a);
            acc[n][0] = fmaf(p, x0, acc[n][0]);
            acc[n][1] = fmaf(p, x1, acc[n][1]);
            acc[n][2] = fmaf(p, x2, acc[n][2]);
            acc[n][3] = fmaf(p, x3, acc[n][3]);
            acc[n][4] = fmaf(p, x4, acc[n][4]);
            acc[n][5] = fmaf(p, x5, acc[n][5]);
        }
    }

    // butterfly reduce across the 64 lanes
#pragma unroll
    for (int n = 0; n < 8; ++n)
#pragma unroll
        for (int c = 0; c < 6; ++c) {
            float v = acc[n][c];
            for (int d = 1; d < 64; d <<= 1) v += __shfl_xor(v, d, 64);
            acc[n][c] = v;
        }

    if (lane == 0) {
        float w0 = nw[0], w1 = nw[1], w2 = nw[2], w3 = nw[3], w4 = nw[4], w5 = nw[5];
        float b0 = nb[0], b1 = nb[1], b2 = nb[2], b3 = nb[3], b4 = nb[4], b5 = nb[5];
        float wc[6] = {w0, w1, w2, w3, w4, w5};
        float bc[6] = {b0, b1, b2, b3, b4, b5};
#pragma unroll
        for (int n = 0; n < 8; ++n) {
            float mu = (acc[n][0] + acc[n][1] + acc[n][2] +
                        acc[n][3] + acc[n][4] + acc[n][5]) * (1.f / 6.f);
            float var = 0.f;
#pragma unroll
            for (int c = 0; c < 6; ++c) {
                float dv = acc[n][c] - mu;
                var = fmaf(dv, dv, var);
            }
            var *= (1.f / 6.f);
            float inv = rsqrtf(var + 1e-5f);
#pragma unroll
            for (int c = 0; c < 6; ++c)
                out[((size_t)(b * CH + c)) * HW + n0 + n] =
                    (acc[n][c] - mu) * inv * wc[c] + bc[c];
        }
    }
}

// ---------------------------------------------------------------------------
extern "C" void kernel_launch(void* const* d_in, const int* in_sizes, int n_in,
                              void* d_out, int out_size, void* d_ws, size_t ws_size,
                              hipStream_t stream)
{
    const float* x           = (const float*)d_in[0];
    const float* feature     = (const float*)d_in[1];
    const float* fc1_w       = (const float*)d_in[2];
    const float* fc1_b       = (const float*)d_in[3];
    const float* fc2_w       = (const float*)d_in[4];
    const float* fc2_b       = (const float*)d_in[5];
    const float* logit_scale = (const float*)d_in[6];
    const float* norm_w      = (const float*)d_in[7];
    const float* norm_b      = (const float*)d_in[8];
    float* out = (float*)d_out;

    float* ws = (float*)d_ws;
    // workspace layout (floats)
    float* featT = ws;                       // 442368
    float* hT    = featT + 442368;           // 442368
    float* p1    = hT    + 442368;           // 8  * 442368 = 3538944
    float* p2    = p1    + 3538944;          // 18 * 196608 = 3538944
    float* fTs   = p2    + 3538944;          // 196608
    float* xT    = fTs   + 196608;           // 196608
    float* Dpart = xT    + 196608;           // 262144
    float* Rrec  = Dpart + 262144;           // 32768
    // total ~8.65M floats = 34.6 MB

    // 1) transposes
    prep_kernel<<<(442368 + 196608 + 255) / 256, 256, 0, stream>>>(x, feature, featT, xT);
    // 2) fc1: N=9216, K=9216, 8 k-chunks of 1152 -> grid 144x8
    skinny48_gemm<<<dim3(144, 8), 256, 0, stream>>>(fc1_w, featT, p1, FF, 1152);
    // 3) reduce + bias + relu -> hT
    reduce_relu<<<(FF * RC + 255) / 256, 256, 0, stream>>>(p1, fc1_b, hT, 8);
    // 4) fc2: N=4096, K=9216, 18 k-chunks of 512 -> grid 64x18
    skinny48_gemm<<<dim3(64, 18), 256, 0, stream>>>(fc2_w, hT, p2, FF, 512);
    // 5) reduce + bias + logit-scale fold -> fTs[b][m][c]
    reduce_scale<<<(HW * RC + 255) / 256, 256, 0, stream>>>(p2, fc2_b, logit_scale, fTs, 18);
    // 6) column sums of exp(t) over n (8 n-chunks)
    colsum_kernel<<<dim3(16, BATCH, 8), 256, 0, stream>>>(fTs, xT, Dpart);
    // 7) combine to reciprocal
    combineD_kernel<<<(BATCH * HW + 255) / 256, 256, 0, stream>>>(Dpart, Rrec);
    // 8) attention output + LayerNorm, writes [B][C][HW]
    attn_out_kernel<<<dim3(128, BATCH), 256, 0, stream>>>(fTs, xT, Rrec, norm_w, norm_b, out);
}

// Round 2
// 802.674 us; speedup vs baseline: 1.8313x; 1.8313x over previous
//
#include <hip/hip_runtime.h>
#include <math.h>

// Problem dims
#define BATCH 8
#define CH 6
#define HW 4096
#define FF 9216
#define RC 48            // BATCH*CH rows
#define LOG2E 1.44269504088896340736f
#define LN100 4.6051701859880913680f

// ---------------- prep: build featT[k][48] and xT[b][n][6] ----------------
__global__ __launch_bounds__(256) void prep_kernel(
    const float* __restrict__ x, const float* __restrict__ feature,
    float* __restrict__ featT, float* __restrict__ xT)
{
    int i = blockIdx.x * 256 + threadIdx.x;
    if (i < FF * RC) {
        int k = i / RC, r = i - k * RC;
        featT[i] = feature[(size_t)r * FF + k];
    } else {
        int t = i - FF * RC;
        if (t < BATCH * HW * CH) {
            int c = t % CH;
            int n = (t / CH) & (HW - 1);
            int b = t / (HW * CH);
            xT[t] = x[((size_t)(b * CH + c)) * HW + n];
        }
    }
}

// ---------------- skinny GEMM, register-blocked -----------------------------
// W: [N][K] row-major. AT: [K][48]. part: [nchunks][N][48].
// Block tile: 128 j x 48 r. 256 threads: tx=t&31 (j=32q+tx), ty=t>>5 (r=6ty+i).
// W tile staged [32k][128j] with XOR-swizzle phys_j = 32q + (jj ^ k).
__global__ __launch_bounds__(256) void gemm48(
    const float* __restrict__ W, const float* __restrict__ AT,
    float* __restrict__ part, int K, int kchunk)
{
    __shared__ float ldsW[32 * 128];   // 16 KB
    __shared__ float ldsA[32 * 48];    // 6 KB
    const int t = threadIdx.x;
    const int tx = t & 31;
    const int ty = t >> 5;          // 0..7
    const int j0 = blockIdx.x * 128;
    const int kbase = blockIdx.y * kchunk;
    const int ntiles = kchunk >> 5;

    const int wrow = t >> 3;        // 0..31 (staging row within round)
    const int wk4  = (t & 7) * 4;   // 0,4,...,28 (staging k)

    float acc[4][6];
#pragma unroll
    for (int q = 0; q < 4; ++q)
#pragma unroll
        for (int i = 0; i < 6; ++i) acc[q][i] = 0.f;

    for (int tile = 0; tile < ntiles; ++tile) {
        const int kt = kbase + tile * 32;
        // ---- stage W tile: 128 rows x 32 k, transposed into [k][128] ----
#pragma unroll
        for (int rnd = 0; rnd < 4; ++rnd) {
            int row = rnd * 32 + wrow;
            float4 v = *(const float4*)(W + (size_t)(j0 + row) * K + kt + wk4);
            float* dst = ldsW + rnd * 32;
            dst[(wk4 + 0) * 128 + (wrow ^ (wk4 + 0))] = v.x;
            dst[(wk4 + 1) * 128 + (wrow ^ (wk4 + 1))] = v.y;
            dst[(wk4 + 2) * 128 + (wrow ^ (wk4 + 2))] = v.z;
            dst[(wk4 + 3) * 128 + (wrow ^ (wk4 + 3))] = v.w;
        }
        // ---- stage A tile: 32 k x 48 r, linear ----
        {
            const float2* asrc = (const float2*)(AT + (size_t)kt * RC);
            float2* adst = (float2*)ldsA;
            adst[t]       = asrc[t];
            adst[t + 256] = asrc[t + 256];
            adst[t + 512] = asrc[t + 512];
        }
        __syncthreads();
        // ---- compute ----
#pragma unroll 4
        for (int k = 0; k < 32; ++k) {
            const float* wr = ldsW + k * 128;
            int js = tx ^ k;
            float w0 = wr[js];
            float w1 = wr[32 + js];
            float w2 = wr[64 + js];
            float w3 = wr[96 + js];
            const float* ar = ldsA + k * RC + 6 * ty;
            float a0 = ar[0], a1 = ar[1], a2 = ar[2];
            float a3 = ar[3], a4 = ar[4], a5 = ar[5];
            acc[0][0] = fmaf(w0, a0, acc[0][0]);
            acc[0][1] = fmaf(w0, a1, acc[0][1]);
            acc[0][2] = fmaf(w0, a2, acc[0][2]);
            acc[0][3] = fmaf(w0, a3, acc[0][3]);
            acc[0][4] = fmaf(w0, a4, acc[0][4]);
            acc[0][5] = fmaf(w0, a5, acc[0][5]);
            acc[1][0] = fmaf(w1, a0, acc[1][0]);
            acc[1][1] = fmaf(w1, a1, acc[1][1]);
            acc[1][2] = fmaf(w1, a2, acc[1][2]);
            acc[1][3] = fmaf(w1, a3, acc[1][3]);
            acc[1][4] = fmaf(w1, a4, acc[1][4]);
            acc[1][5] = fmaf(w1, a5, acc[1][5]);
            acc[2][0] = fmaf(w2, a0, acc[2][0]);
            acc[2][1] = fmaf(w2, a1, acc[2][1]);
            acc[2][2] = fmaf(w2, a2, acc[2][2]);
            acc[2][3] = fmaf(w2, a3, acc[2][3]);
            acc[2][4] = fmaf(w2, a4, acc[2][4]);
            acc[2][5] = fmaf(w2, a5, acc[2][5]);
            acc[3][0] = fmaf(w3, a0, acc[3][0]);
            acc[3][1] = fmaf(w3, a1, acc[3][1]);
            acc[3][2] = fmaf(w3, a2, acc[3][2]);
            acc[3][3] = fmaf(w3, a3, acc[3][3]);
            acc[3][4] = fmaf(w3, a4, acc[3][4]);
            acc[3][5] = fmaf(w3, a5, acc[3][5]);
        }
        __syncthreads();
    }

    // ---- write partials: part[(chunk*N + j0 + j)*48 + r] ----
    const int N = gridDim.x * 128;
    float* base = part + ((size_t)blockIdx.y * N + j0) * RC + 6 * ty;
#pragma unroll
    for (int q = 0; q < 4; ++q) {
        float* dst = base + (size_t)(q * 32 + tx) * RC;
        float2 v0 = make_float2(acc[q][0], acc[q][1]);
        float2 v1 = make_float2(acc[q][2], acc[q][3]);
        float2 v2 = make_float2(acc[q][4], acc[q][5]);
        *(float2*)(dst + 0) = v0;
        *(float2*)(dst + 2) = v1;
        *(float2*)(dst + 4) = v2;
    }
}

// ---------------- reduce1: hT[j][r] = relu(sum_c p1 + b1[j]) ----------------
__global__ __launch_bounds__(256) void reduce_relu(
    const float* __restrict__ part, const float* __restrict__ bias,
    float* __restrict__ hT, int nchunks)
{
    int i = blockIdx.x * 256 + threadIdx.x;
    const int total = FF * RC;
    if (i >= total) return;
    float s = 0.f;
    for (int c = 0; c < nchunks; ++c) s += part[(size_t)c * total + i];
    int j = i / RC;
    s += bias[j];
    hT[i] = fmaxf(s, 0.f);
}

// ---- reduce2: fTs[b][m][c] = (sum_c p2 + b2[m]) * ls[m] * LOG2E -----------
__global__ __launch_bounds__(256) void reduce_scale(
    const float* __restrict__ part, const float* __restrict__ bias,
    const float* __restrict__ logit_scale, float* __restrict__ fTs, int nchunks)
{
    int i = blockIdx.x * 256 + threadIdx.x;
    const int total = HW * RC;
    if (i >= total) return;
    float s = 0.f;
    for (int c = 0; c < nchunks; ++c) s += part[(size_t)c * total + i];
    int m = i / RC, rc = i - m * RC;
    int b = rc / CH, cc = rc - b * CH;
    float lv = fminf(logit_scale[m], LN100);
    float ls = __builtin_amdgcn_exp2f(lv * LOG2E);
    s = (s + bias[m]) * ls * LOG2E;
    fTs[((size_t)b * HW + m) * CH + cc] = s;
}

// ---------------- pass A: column sums D over an n-chunk --------------------
__global__ __launch_bounds__(256) void colsum_kernel(
    const float* __restrict__ fTs, const float* __restrict__ xT,
    float* __restrict__ Dpart)
{
    __shared__ float xs[512 * CH];   // 12 KB
    const int t = threadIdx.x;
    const int b = blockIdx.y;
    const int ns = blockIdx.z;
    // stage the 512-row x chunk
    {
        const float4* src = (const float4*)(xT + ((size_t)b * HW + ns * 512) * CH);
        float4* dst = (float4*)xs;
        dst[t]       = src[t];
        dst[t + 256] = src[t + 256];
        dst[t + 512] = src[t + 512];
    }
    __syncthreads();

    int m = blockIdx.x * 256 + t;
    const float2* f2 = (const float2*)(fTs + ((size_t)b * HW + m) * CH);
    float2 fa = f2[0], fb = f2[1], fc = f2[2];
    float s0 = fa.x, s1 = fa.y, s2 = fb.x, s3 = fb.y, s4 = fc.x, s5 = fc.y;

    float D = 0.f;
#pragma unroll 4
    for (int n = 0; n < 512; ++n) {
        const float* xn = xs + n * CH;   // wave-uniform -> LDS broadcast
        float a = fmaf(s0, xn[0], fmaf(s1, xn[1], fmaf(s2, xn[2],
                  fmaf(s3, xn[3], fmaf(s4, xn[4], s5 * xn[5])))));
        D += __builtin_amdgcn_exp2f(a);
    }
    Dpart[((size_t)b * 8 + ns) * HW + m] = D;
}

// ---- combine D -> write pre-scaled xR[b][m][c] = x[c,m] / D ---------------
__global__ __launch_bounds__(256) void combineD_kernel(
    const float* __restrict__ Dpart, const float* __restrict__ xT,
    float* __restrict__ xR)
{
    int i = blockIdx.x * 256 + threadIdx.x;
    if (i >= BATCH * HW) return;
    int b = i >> 12, m = i & (HW - 1);
    float s = 0.f;
    for (int ns = 0; ns < 8; ++ns) s += Dpart[((size_t)b * 8 + ns) * HW + m];
    float r = 1.0f / s;
    const float2* xs = (const float2*)(xT + (size_t)i * CH);
    float2 v0 = xs[0], v1 = xs[1], v2 = xs[2];
    float2* xd = (float2*)(xR + (size_t)i * CH);
    xd[0] = make_float2(v0.x * r, v0.y * r);
    xd[1] = make_float2(v1.x * r, v1.y * r);
    xd[2] = make_float2(v2.x * r, v2.y * r);
}

// -------- pass B: out[b,n,c] = LN( sum_m exp(t) * xR[m,c] ) ----------------
__global__ __launch_bounds__(256) void attn_out_kernel(
    const float* __restrict__ fTs, const float* __restrict__ xT,
    const float* __restrict__ xR, const float* __restrict__ nw,
    const float* __restrict__ nb, float* __restrict__ out)
{
    int b = blockIdx.y;
    int wv = threadIdx.x >> 6;
    int lane = threadIdx.x & 63;
    int n0 = (blockIdx.x * 4 + wv) * 8;

    const float* __restrict__ xb = xT + (size_t)b * HW * CH;
    float xn[8][6];
#pragma unroll
    for (int n = 0; n < 8; ++n)
#pragma unroll
        for (int c = 0; c < 6; ++c) xn[n][c] = xb[(size_t)(n0 + n) * CH + c];

    const float* __restrict__ frb = fTs + (size_t)b * HW * CH;
    const float* __restrict__ xrb = xR + (size_t)b * HW * CH;

    float acc[8][6];
#pragma unroll
    for (int n = 0; n < 8; ++n)
#pragma unroll
        for (int c = 0; c < 6; ++c) acc[n][c] = 0.f;

    for (int i = 0; i < 64; ++i) {
        int m = i * 64 + lane;
        const float2* f2 = (const float2*)(frb + (size_t)m * CH);
        float2 fa = f2[0], fb = f2[1], fc = f2[2];
        const float2* x2 = (const float2*)(xrb + (size_t)m * CH);
        float2 xa = x2[0], xb2 = x2[1], xc = x2[2];
        float f0 = fa.x, f1 = fa.y, f2v = fb.x, f3 = fb.y, f4 = fc.x, f5 = fc.y;
#pragma unroll
        for (int n = 0; n < 8; ++n) {
            float a = fmaf(f0, xn[n][0], fmaf(f1, xn[n][1], fmaf(f2v, xn[n][2],
                      fmaf(f3, xn[n][3], fmaf(f4, xn[n][4], f5 * xn[n][5])))));
            float p = __builtin_amdgcn_exp2f(a);
            acc[n][0] = fmaf(p, xa.x, acc[n][0]);
            acc[n][1] = fmaf(p, xa.y, acc[n][1]);
            acc[n][2] = fmaf(p, xb2.x, acc[n][2]);
            acc[n][3] = fmaf(p, xb2.y, acc[n][3]);
            acc[n][4] = fmaf(p, xc.x, acc[n][4]);
            acc[n][5] = fmaf(p, xc.y, acc[n][5]);
        }
    }

    // butterfly reduce across the 64 lanes
#pragma unroll
    for (int n = 0; n < 8; ++n)
#pragma unroll
        for (int c = 0; c < 6; ++c) {
            float v = acc[n][c];
            for (int d = 1; d < 64; d <<= 1) v += __shfl_xor(v, d, 64);
            acc[n][c] = v;
        }

    if (lane == 0) {
        float wc[6], bc[6];
#pragma unroll
        for (int c = 0; c < 6; ++c) { wc[c] = nw[c]; bc[c] = nb[c]; }
#pragma unroll
        for (int n = 0; n < 8; ++n) {
            float mu = (acc[n][0] + acc[n][1] + acc[n][2] +
                        acc[n][3] + acc[n][4] + acc[n][5]) * (1.f / 6.f);
            float var = 0.f;
#pragma unroll
            for (int c = 0; c < 6; ++c) {
                float dv = acc[n][c] - mu;
                var = fmaf(dv, dv, var);
            }
            var *= (1.f / 6.f);
            float inv = rsqrtf(var + 1e-5f);
#pragma unroll
            for (int c = 0; c < 6; ++c)
                out[((size_t)(b * CH + c)) * HW + n0 + n] =
                    (acc[n][c] - mu) * inv * wc[c] + bc[c];
        }
    }
}

// ---------------------------------------------------------------------------
extern "C" void kernel_launch(void* const* d_in, const int* in_sizes, int n_in,
                              void* d_out, int out_size, void* d_ws, size_t ws_size,
                              hipStream_t stream)
{
    const float* x           = (const float*)d_in[0];
    const float* feature     = (const float*)d_in[1];
    const float* fc1_w       = (const float*)d_in[2];
    const float* fc1_b       = (const float*)d_in[3];
    const float* fc2_w       = (const float*)d_in[4];
    const float* fc2_b       = (const float*)d_in[5];
    const float* logit_scale = (const float*)d_in[6];
    const float* norm_w      = (const float*)d_in[7];
    const float* norm_b      = (const float*)d_in[8];
    float* out = (float*)d_out;

    float* ws = (float*)d_ws;
    // workspace layout (floats)
    float* featT = ws;                       // 442368
    float* hT    = featT + 442368;           // 442368
    float* p1    = hT    + 442368;           // 8 * 442368 = 3538944
    float* p2    = p1    + 3538944;          // 8 * 196608 = 1572864
    float* fTs   = p2    + 1572864;          // 196608
    float* xT    = fTs   + 196608;           // 196608
    float* Dpart = xT    + 196608;           // 262144
    float* xR    = Dpart + 262144;           // 196608
    // total ~6.85M floats = 27.4 MB

    // 1) transposes
    prep_kernel<<<(442368 + 196608 + 255) / 256, 256, 0, stream>>>(x, feature, featT, xT);
    // 2) fc1: N=9216, K=9216, 8 k-chunks of 1152 -> grid 72x8
    gemm48<<<dim3(72, 8), 256, 0, stream>>>(fc1_w, featT, p1, FF, 1152);
    // 3) reduce + bias + relu -> hT
    reduce_relu<<<(FF * RC + 255) / 256, 256, 0, stream>>>(p1, fc1_b, hT, 8);
    // 4) fc2: N=4096, K=9216, 8 k-chunks of 1152 -> grid 32x8
    gemm48<<<dim3(32, 8), 256, 0, stream>>>(fc2_w, hT, p2, FF, 1152);
    // 5) reduce + bias + logit-scale fold -> fTs[b][m][c]
    reduce_scale<<<(HW * RC + 255) / 256, 256, 0, stream>>>(p2, fc2_b, logit_scale, fTs, 8);
    // 6) column sums of exp(t) over n (8 n-chunks)
    colsum_kernel<<<dim3(16, BATCH, 8), 256, 0, stream>>>(fTs, xT, Dpart);
    // 7) combine to reciprocal, fold into xR
    combineD_kernel<<<(BATCH * HW + 255) / 256, 256, 0, stream>>>(Dpart, xT, xR);
    // 8) attention output + LayerNorm, writes [B][C][HW]
    attn_out_kernel<<<dim3(128, BATCH), 256, 0, stream>>>(fTs, xT, xR, norm_w, norm_b, out);
}